// Round 10
// baseline (194.428 us; speedup 1.0000x reference)
//
#include <hip/hip_runtime.h>
#include <hip/hip_bf16.h>

// VectorQuantizer: z (32, 64, 4096) f32, emb (1024, 64) f32.
// argmin_j ||z - emb_j||^2 per column-vector, output emb[argmin] in (B,C,S).
//
// R10 == R9 == R8 == R7 (never ran: four GPU acquisition timeouts). Unchanged.
// R7 = R6 (passed, absmax 0.0, 172us) with the two structural wastes removed:
//  - single-block vq_setup (~77us serial) -> esq/e_max computed per-block in
//    vq_main (bit-identical chains); setup kernel reduced to a parallel bf16
//    convert of emb (64 blocks, ~3us).
//  - LDS 44032 -> 40584 B (drop thr[], queue 1024->416) => 4 blocks/CU
//    (was 3), 1024 blocks = exactly one scheduling round, no 33% tail.
//  - z staging split across all 256 threads (2x parallel, still coalesced).
// Phases A/B/C and the MFMA fragment code are byte-identical to R6.
//
// Correctness structure (unchanged): bf16 MFMA screen -> per-row approx min
// (A); rescan pushing codes within thr of min (B); exact fp32 rescore with
// the R1-verified chain + (d,j)-lex atomicMin => numpy first-index argmin (C).
// thr = 0.025*e_max*||z|| + 1e-4 provably covers bf16 screen error; queue
// overflow (>QMAX) falls back to full exact rescan. Correctness never
// depends on screen precision.

typedef float f32x4 __attribute__((ext_vector_type(4)));
typedef short s16x8 __attribute__((ext_vector_type(8)));

constexpr int N_EMB = 1024;
constexpr int CDIM  = 64;
constexpr int SEQ   = 4096;
constexpr int BS    = 32;
constexpr int NROWS = BS * SEQ;     // 131072
constexpr int RPB   = 128;          // rows per block -> 1024 blocks
constexpr int TPB   = 256;          // 4 waves; codes split 256/wave
constexpr int QMAX  = 416;          // candidate queue (expect ~205/block)

constexpr size_t WS_EBF_BYTES = (size_t)N_EMB * CDIM * 2;   // 128 KB

__device__ __forceinline__ unsigned enc_f32(float f) {
    unsigned u = __float_as_uint(f);
    return (u & 0x80000000u) ? ~u : (u | 0x80000000u);   // order-preserving
}
__device__ __forceinline__ float dec_f32(unsigned k) {
    return __uint_as_float((k & 0x80000000u) ? (k & 0x7fffffffu) : ~k);
}
__device__ __forceinline__ short f2bf(float x) {
    __hip_bfloat16 h = __float2bfloat16(x);               // RNE
    return *reinterpret_cast<short*>(&h);
}
__device__ __forceinline__ float pair8(const float r[8]) {
    return __fadd_rn(
        __fadd_rn(__fadd_rn(r[0], r[1]), __fadd_rn(r[2], r[3])),
        __fadd_rn(__fadd_rn(r[4], r[5]), __fadd_rn(r[6], r[7])));
}

// -------- setup: emb -> bf16, fully parallel (64 blocks x 256 thr) --------
__global__ __launch_bounds__(256) void vq_setup_ebf(
    const float* __restrict__ emb, unsigned short* __restrict__ ebf)
{
    const float2* e2 = reinterpret_cast<const float2*>(emb);
    unsigned int* eb2 = reinterpret_cast<unsigned int*>(ebf);
    const int i0 = blockIdx.x * 512 + threadIdx.x;
    #pragma unroll
    for (int u = 0; u < 2; ++u) {
        const int i = i0 + u * 256;           // 64*512 = 32768 u32 total
        const float2 v = e2[i];
        eb2[i] = (unsigned)(unsigned short)f2bf(v.x)
               | ((unsigned)(unsigned short)f2bf(v.y) << 16);
    }
}

// ---------------- main ----------------
__global__ __launch_bounds__(TPB, 4) void vq_main(
    const float* __restrict__ z, const float* __restrict__ emb,
    const unsigned short* __restrict__ ebf, float* __restrict__ out)
{
    __shared__ float zf[RPB * 64];          // 32768 B, XOR-swizzled fp32 z rows
    __shared__ float esq[N_EMB];            // 4096 B
    __shared__ float zsq[RPB];              // 512 B
    __shared__ unsigned int rowmin[RPB];    // 512 B   enc(min d') per row
    __shared__ unsigned long long keys[RPB];// 1024 B
    __shared__ unsigned int queue[QMAX];    // 1664 B
    __shared__ unsigned int qcnt;           // 4 B
    __shared__ unsigned int emax_u;         // 4 B     -> total 40584 B

    const int t    = threadIdx.x;
    const int lane = t & 63;
    const int wv   = t >> 6;                // 0..3 (code range 256/wave)
    const int g    = lane >> 4;             // k-group / D-row group
    const int ln   = lane & 15;             // A-row (code) / B-col (z-row)
    const int row0 = blockIdx.x * RPB;
    const int b    = row0 >> 12;
    const int s0   = row0 & (SEQ - 1);

    // ---------- S0: init ----------
    if (t == 0) { qcnt = 0; emax_u = 0; }
    if (t < RPB) { rowmin[t] = 0xFFFFFFFFu; keys[t] = ~0ull; }
    __syncthreads();

    // ---------- S1: esq (4 codes/thread, bit-identical chain) + z stage ----
    {
        float lmax = 0.0f;
        #pragma unroll
        for (int i = 0; i < 4; ++i) {
            const int j = t + 256 * i;
            const float* e = emb + j * CDIM;
            float r[8];
            #pragma unroll
            for (int q = 0; q < 8; ++q) r[q] = __fmul_rn(e[q], e[q]);
            #pragma unroll
            for (int kk = 8; kk < 64; kk += 8) {
                #pragma unroll
                for (int q = 0; q < 8; ++q)
                    r[q] = __fadd_rn(r[q], __fmul_rn(e[kk + q], e[kk + q]));
            }
            const float v = pair8(r);
            esq[j] = v;
            lmax = fmaxf(lmax, v);
        }
        atomicMax(&emax_u, __float_as_uint(lmax));   // esq >= 0: bits monotone
    }
    {
        // 256 threads stage 128 rows: row = t&127, k-half = t>>7 (coalesced:
        // at fixed k, lanes cover consecutive s). Same swizzled layout as R6.
        const int row = t & 127;
        const int kh  = t >> 7;
        const int swz = (row & 7) << 2;
        const float* zp = z + (size_t)b * CDIM * SEQ + s0 + row;
        #pragma unroll
        for (int kb = kh * 32; kb < kh * 32 + 32; kb += 4) {
            f32x4 v;
            #pragma unroll
            for (int u = 0; u < 4; ++u) v[u] = zp[(size_t)(kb + u) * SEQ];
            *reinterpret_cast<f32x4*>(&zf[(row << 6) | (kb ^ swz)]) = v;
        }
    }
    __syncthreads();

    // ---------- S2: zsq from LDS (t<128; same sequential chain as R6) ------
    if (t < RPB) {
        const int row = t;
        const int swz = (row & 7) << 2;
        float r[8];
        #pragma unroll
        for (int q = 0; q < 8; ++q) r[q] = 0.0f;
        #pragma unroll
        for (int k = 0; k < 64; ++k) {
            const float x = zf[(row << 6) | (k ^ swz)];
            r[k & 7] = __fadd_rn(r[k & 7], __fmul_rn(x, x));   // 0+x^2 exact
        }
        zsq[row] = pair8(r);
    }

    // ---------- S3: z fragments (8 row-tiles x 2 k-steps) in VGPRs ----------
    s16x8 zfr[8][2];
    #pragma unroll
    for (int rt = 0; rt < 8; ++rt) {
        const int row = rt * 16 + ln;
        const int swz = (row & 7) << 2;
        #pragma unroll
        for (int ks = 0; ks < 2; ++ks) {
            const int kb = g * 8 + ks * 32;
            const f32x4 a = *reinterpret_cast<const f32x4*>(&zf[(row << 6) | (kb ^ swz)]);
            const f32x4 c = *reinterpret_cast<const f32x4*>(&zf[(row << 6) | ((kb + 4) ^ swz)]);
            s16x8 fr;
            fr[0] = f2bf(a[0]); fr[1] = f2bf(a[1]); fr[2] = f2bf(a[2]); fr[3] = f2bf(a[3]);
            fr[4] = f2bf(c[0]); fr[5] = f2bf(c[1]); fr[6] = f2bf(c[2]); fr[7] = f2bf(c[3]);
            zfr[rt][ks] = fr;
        }
    }

    const int cw = wv * 256;

    // ---------- phase A: scan, per-row approx min (identical to R6) --------
    float mrun[8];
    #pragma unroll
    for (int rt = 0; rt < 8; ++rt) mrun[rt] = INFINITY;

    #pragma unroll 1
    for (int q = 0; q < 4; ++q) {
        s16x8 efr[4][2];
        f32x4 eq[4];
        #pragma unroll
        for (int ct = 0; ct < 4; ++ct) {
            const int code = cw + q * 64 + ct * 16 + ln;
            const unsigned short* ep = ebf + code * 64;
            #pragma unroll
            for (int ks = 0; ks < 2; ++ks)
                efr[ct][ks] = *reinterpret_cast<const s16x8*>(ep + g * 8 + ks * 32);
            eq[ct] = *reinterpret_cast<const f32x4*>(&esq[cw + q * 64 + ct * 16 + g * 4]);
        }
        #pragma unroll
        for (int rt = 0; rt < 8; ++rt) {
            #pragma unroll
            for (int ct = 0; ct < 4; ++ct) {
                f32x4 acc = {0.f, 0.f, 0.f, 0.f};
                acc = __builtin_amdgcn_mfma_f32_16x16x32_bf16(efr[ct][0], zfr[rt][0], acc, 0, 0, 0);
                acc = __builtin_amdgcn_mfma_f32_16x16x32_bf16(efr[ct][1], zfr[rt][1], acc, 0, 0, 0);
                const float d0 = __fmaf_rn(-2.f, acc[0], eq[ct][0]);
                const float d1 = __fmaf_rn(-2.f, acc[1], eq[ct][1]);
                const float d2 = __fmaf_rn(-2.f, acc[2], eq[ct][2]);
                const float d3 = __fmaf_rn(-2.f, acc[3], eq[ct][3]);
                mrun[rt] = fminf(mrun[rt],
                                 fminf(fminf(d0, d1), fminf(d2, d3)));
            }
        }
    }
    #pragma unroll
    for (int rt = 0; rt < 8; ++rt)
        atomicMin(&rowmin[rt * 16 + ln], enc_f32(mrun[rt]));
    __syncthreads();

    // ---------- phase B: rescan, push candidates (thr computed inline) -----
    const float emax = sqrtf(__uint_as_float(emax_u)) * 1.0001f;
    float cthr[8];
    #pragma unroll
    for (int rt = 0; rt < 8; ++rt) {
        const int row = rt * 16 + ln;
        const float thr_row = __fmaf_rn(0.025f * emax, sqrtf(zsq[row]), 1e-4f);
        cthr[rt] = dec_f32(rowmin[row]) + thr_row;
    }
    #pragma unroll 1
    for (int q = 0; q < 4; ++q) {
        s16x8 efr[4][2];
        f32x4 eq[4];
        #pragma unroll
        for (int ct = 0; ct < 4; ++ct) {
            const int code = cw + q * 64 + ct * 16 + ln;
            const unsigned short* ep = ebf + code * 64;
            #pragma unroll
            for (int ks = 0; ks < 2; ++ks)
                efr[ct][ks] = *reinterpret_cast<const s16x8*>(ep + g * 8 + ks * 32);
            eq[ct] = *reinterpret_cast<const f32x4*>(&esq[cw + q * 64 + ct * 16 + g * 4]);
        }
        #pragma unroll
        for (int rt = 0; rt < 8; ++rt) {
            #pragma unroll
            for (int ct = 0; ct < 4; ++ct) {
                f32x4 acc = {0.f, 0.f, 0.f, 0.f};
                acc = __builtin_amdgcn_mfma_f32_16x16x32_bf16(efr[ct][0], zfr[rt][0], acc, 0, 0, 0);
                acc = __builtin_amdgcn_mfma_f32_16x16x32_bf16(efr[ct][1], zfr[rt][1], acc, 0, 0, 0);
                const int row  = rt * 16 + ln;
                const int cbas = cw + q * 64 + ct * 16 + g * 4;
                #pragma unroll
                for (int rr = 0; rr < 4; ++rr) {
                    const float dd = __fmaf_rn(-2.f, acc[rr], eq[ct][rr]);
                    if (dd <= cthr[rt]) {
                        const unsigned idx = atomicAdd(&qcnt, 1u);
                        if (idx < (unsigned)QMAX)
                            queue[idx] = ((unsigned)row << 10) | (unsigned)(cbas + rr);
                    }
                }
            }
        }
    }
    __syncthreads();

    // ---------- phase C: exact rescore (R1 chain, bit-identical) ----------
    const unsigned qtot = qcnt;
    if (qtot <= (unsigned)QMAX) {
        for (unsigned i = t; i < qtot; i += TPB) {
            const unsigned pk = queue[i];
            const int row = (int)(pk >> 10);
            const int j   = (int)(pk & 1023u);
            const int swz = (row & 7) << 2;
            const float* e = emb + j * CDIM;
            float acc = 0.0f;
            #pragma unroll
            for (int k = 0; k < CDIM; ++k)
                acc = __fmaf_rn(zf[(row << 6) | (k ^ swz)], e[k], acc);
            const float d = __fmaf_rn(-2.f, acc, __fadd_rn(zsq[row], esq[j]));
            const unsigned long long key =
                ((unsigned long long)enc_f32(d) << 32) | (unsigned)j;
            atomicMin(&keys[row], key);          // (d asc, then j asc)
        }
    } else {
        // queue overflowed (never expected): provably-correct full rescan
        for (int i = t; i < RPB * N_EMB; i += TPB) {
            const int row = i >> 10;
            const int j   = i & 1023;
            const int swz = (row & 7) << 2;
            const float* e = emb + j * CDIM;
            float acc = 0.0f;
            #pragma unroll
            for (int k = 0; k < CDIM; ++k)
                acc = __fmaf_rn(zf[(row << 6) | (k ^ swz)], e[k], acc);
            const float d = __fmaf_rn(-2.f, acc, __fadd_rn(zsq[row], esq[j]));
            const unsigned long long key =
                ((unsigned long long)enc_f32(d) << 32) | (unsigned)j;
            atomicMin(&keys[row], key);
        }
    }
    __syncthreads();

    // ---------- output: gather emb[jmin] -> (b, c, s) ----------
    {
        const int row = t & 127;
        const int h   = t >> 7;              // c-half
        int jm = (int)(keys[row] & 0xFFFFFFFFull);
        if ((unsigned)jm >= (unsigned)N_EMB) jm = 0;   // safety
        const float* e = emb + (size_t)jm * CDIM + h * 32;
        float* op = out + (size_t)b * CDIM * SEQ + s0 + row;
        #pragma unroll
        for (int c = 0; c < 32; c += 4) {
            const f32x4 v = *reinterpret_cast<const f32x4*>(e + c);
            op[(size_t)(h * 32 + c + 0) * SEQ] = v[0];
            op[(size_t)(h * 32 + c + 1) * SEQ] = v[1];
            op[(size_t)(h * 32 + c + 2) * SEQ] = v[2];
            op[(size_t)(h * 32 + c + 3) * SEQ] = v[3];
        }
    }
}

// ---------------- fallback (R1, known-correct, ~439 us) ----------------
__global__ __launch_bounds__(256, 2) void vq_fallback(
    const float* __restrict__ z, const float* __restrict__ emb,
    float* __restrict__ out)
{
    __shared__ float esq[N_EMB];
    for (int j = threadIdx.x; j < N_EMB; j += 256) {
        const float* e = emb + j * CDIM;
        float r[8];
        #pragma unroll
        for (int q = 0; q < 8; ++q) r[q] = __fmul_rn(e[q], e[q]);
        #pragma unroll
        for (int i = 8; i < 64; i += 8)
            #pragma unroll
            for (int q = 0; q < 8; ++q)
                r[q] = __fadd_rn(r[q], __fmul_rn(e[i + q], e[i + q]));
        esq[j] = pair8(r);
    }
    __syncthreads();
    const int row = blockIdx.x * 256 + threadIdx.x;
    const int b = row >> 12, s = row & (SEQ - 1);
    const float* zp = z + (size_t)b * CDIM * SEQ + s;
    float zv[CDIM];
    #pragma unroll
    for (int k = 0; k < CDIM; ++k) zv[k] = zp[(size_t)k * SEQ];
    float r[8];
    #pragma unroll
    for (int q = 0; q < 8; ++q) r[q] = __fmul_rn(zv[q], zv[q]);
    #pragma unroll
    for (int i = 8; i < 64; i += 8)
        #pragma unroll
        for (int q = 0; q < 8; ++q)
            r[q] = __fadd_rn(r[q], __fmul_rn(zv[i + q], zv[i + q]));
    const float zsq = pair8(r);
    float dmin = INFINITY; int jmin = 0;
    #pragma unroll 1
    for (int j = 0; j < N_EMB; ++j) {
        const float* e = emb + j * CDIM;
        float acc = 0.0f;
        #pragma unroll
        for (int k = 0; k < CDIM; ++k) acc = __fmaf_rn(zv[k], e[k], acc);
        const float d = __fmaf_rn(-2.f, acc, __fadd_rn(zsq, esq[j]));
        if (d < dmin) { dmin = d; jmin = j; }
    }
    const f32x4* ej = reinterpret_cast<const f32x4*>(emb + (size_t)jmin * CDIM);
    float* op = out + (size_t)b * CDIM * SEQ + s;
    #pragma unroll
    for (int q = 0; q < 16; ++q) {
        const f32x4 v = ej[q];
        op[(size_t)(4 * q + 0) * SEQ] = v[0];
        op[(size_t)(4 * q + 1) * SEQ] = v[1];
        op[(size_t)(4 * q + 2) * SEQ] = v[2];
        op[(size_t)(4 * q + 3) * SEQ] = v[3];
    }
}

extern "C" void kernel_launch(void* const* d_in, const int* in_sizes, int n_in,
                              void* d_out, int out_size, void* d_ws, size_t ws_size,
                              hipStream_t stream)
{
    const float* z   = (const float*)d_in[0];
    const float* emb = (const float*)d_in[1];
    float* out = (float*)d_out;

    if (ws_size < WS_EBF_BYTES || d_ws == nullptr) {
        vq_fallback<<<NROWS / 256, 256, 0, stream>>>(z, emb, out);
        return;
    }
    unsigned short* ebf = (unsigned short*)d_ws;

    vq_setup_ebf<<<64, 256, 0, stream>>>(emb, ebf);
    vq_main<<<NROWS / RPB, TPB, 0, stream>>>(z, emb, ebf, out);
}

// Round 11
// 184.837 us; speedup vs baseline: 1.0519x; 1.0519x over previous
//
#include <hip/hip_runtime.h>
#include <hip/hip_bf16.h>

// VectorQuantizer: z (32, 64, 4096) f32, emb (1024, 64) f32.
// argmin_j ||z - emb_j||^2 per column-vector, output emb[argmin] in (B,C,S).
//
// R11: fix R10's regression. R10 counters showed WRITE 85MB / FETCH 45MB
// (vs 33/19 ideal) with VGPR_Count=64: launch_bounds(256,4) caps VGPRs at
// ~256/4=64 while the kernel needs ~110+ (zfr[8][2]=64 regs) -> ~20 regs
// spilled to scratch -> +80MB HBM round-trip, vq_main 95->130us.
// Fix: reduce TRUE register demand, don't cap it:
//  - wave remap: each wave now covers 4 row-tiles x 512 codes (was 8 x 256).
//    zfr[8][2]->zfr[4][2] (-32 regs), mrun/cthr 8->4 (-8). Same total MFMA
//    work; screen coverage per row still spans all 1024 codes (2 waves per
//    row-half, combined via LDS atomicMin as before).
//  - __launch_bounds__(256,2): cap 128, allocator unconstrained at ~110
//    demand -> no spill; runtime occupancy from actual usage (<=128 regs ->
//    16 waves/CU) + LDS 40960*4 = exactly 160KiB -> 4 blocks/CU.
//
// Correctness structure (unchanged, absmax 0.0 pedigree R6/R10): bf16 MFMA
// screen -> per-row approx min (A); rescan pushing codes within thr of min
// (B); exact fp32 rescore with the R1-verified chain + (d,j)-lex atomicMin
// => numpy first-index argmin (C). thr = 0.025*e_max*||z|| + 1e-4 provably
// covers bf16 screen error; queue overflow -> full exact rescan. Correctness
// never depends on screen precision.

typedef float f32x4 __attribute__((ext_vector_type(4)));
typedef short s16x8 __attribute__((ext_vector_type(8)));

constexpr int N_EMB = 1024;
constexpr int CDIM  = 64;
constexpr int SEQ   = 4096;
constexpr int BS    = 32;
constexpr int NROWS = BS * SEQ;     // 131072
constexpr int RPB   = 128;          // rows per block -> 1024 blocks
constexpr int TPB   = 256;          // 4 waves
constexpr int QMAX  = 416;          // candidate queue (expect ~205/block)

constexpr size_t WS_EBF_BYTES = (size_t)N_EMB * CDIM * 2;   // 128 KB

__device__ __forceinline__ unsigned enc_f32(float f) {
    unsigned u = __float_as_uint(f);
    return (u & 0x80000000u) ? ~u : (u | 0x80000000u);   // order-preserving
}
__device__ __forceinline__ float dec_f32(unsigned k) {
    return __uint_as_float((k & 0x80000000u) ? (k & 0x7fffffffu) : ~k);
}
__device__ __forceinline__ short f2bf(float x) {
    __hip_bfloat16 h = __float2bfloat16(x);               // RNE
    return *reinterpret_cast<short*>(&h);
}
__device__ __forceinline__ float pair8(const float r[8]) {
    return __fadd_rn(
        __fadd_rn(__fadd_rn(r[0], r[1]), __fadd_rn(r[2], r[3])),
        __fadd_rn(__fadd_rn(r[4], r[5]), __fadd_rn(r[6], r[7])));
}

// -------- setup: emb -> bf16, fully parallel (64 blocks x 256 thr) --------
__global__ __launch_bounds__(256) void vq_setup_ebf(
    const float* __restrict__ emb, unsigned short* __restrict__ ebf)
{
    const float2* e2 = reinterpret_cast<const float2*>(emb);
    unsigned int* eb2 = reinterpret_cast<unsigned int*>(ebf);
    const int i0 = blockIdx.x * 512 + threadIdx.x;
    #pragma unroll
    for (int u = 0; u < 2; ++u) {
        const int i = i0 + u * 256;           // 64*512 = 32768 u32 total
        const float2 v = e2[i];
        eb2[i] = (unsigned)(unsigned short)f2bf(v.x)
               | ((unsigned)(unsigned short)f2bf(v.y) << 16);
    }
}

// ---------------- main ----------------
__global__ __launch_bounds__(TPB, 2) void vq_main(
    const float* __restrict__ z, const float* __restrict__ emb,
    const unsigned short* __restrict__ ebf, float* __restrict__ out)
{
    __shared__ float zf[RPB * 64];          // 32768 B, XOR-swizzled fp32 z rows
    __shared__ float esq[N_EMB];            // 4096 B
    __shared__ float zsq[RPB];              // 512 B
    __shared__ unsigned int rowmin[RPB];    // 512 B   enc(min d') per row
    __shared__ unsigned long long keys[RPB];// 1024 B
    __shared__ unsigned int queue[QMAX];    // 1664 B
    __shared__ unsigned int qcnt;           // 4 B
    __shared__ unsigned int emax_u;         // 4 B     -> total 40584 B

    const int t    = threadIdx.x;
    const int lane = t & 63;
    const int wv   = t >> 6;                // 0..3
    const int g    = lane >> 4;             // k-group / D-row group
    const int ln   = lane & 15;             // A-row (code) / B-col (z-row)
    // R11 wave remap: wave covers rows rw..rw+63, codes cw..cw+511
    const int cw   = (wv & 1) * 512;
    const int rw   = (wv >> 1) * 64;
    const int row0 = blockIdx.x * RPB;
    const int b    = row0 >> 12;
    const int s0   = row0 & (SEQ - 1);

    // ---------- S0: init ----------
    if (t == 0) { qcnt = 0; emax_u = 0; }
    if (t < RPB) { rowmin[t] = 0xFFFFFFFFu; keys[t] = ~0ull; }
    __syncthreads();

    // ---------- S1: esq (4 codes/thread, bit-identical chain) + z stage ----
    {
        float lmax = 0.0f;
        #pragma unroll
        for (int i = 0; i < 4; ++i) {
            const int j = t + 256 * i;
            const float* e = emb + j * CDIM;
            float r[8];
            #pragma unroll
            for (int q = 0; q < 8; ++q) r[q] = __fmul_rn(e[q], e[q]);
            #pragma unroll
            for (int kk = 8; kk < 64; kk += 8) {
                #pragma unroll
                for (int q = 0; q < 8; ++q)
                    r[q] = __fadd_rn(r[q], __fmul_rn(e[kk + q], e[kk + q]));
            }
            const float v = pair8(r);
            esq[j] = v;
            lmax = fmaxf(lmax, v);
        }
        atomicMax(&emax_u, __float_as_uint(lmax));   // esq >= 0: bits monotone
    }
    {
        // 256 threads stage 128 rows: row = t&127, k-half = t>>7 (coalesced:
        // at fixed k, lanes cover consecutive s). Same swizzled layout as R6.
        const int row = t & 127;
        const int kh  = t >> 7;
        const int swz = (row & 7) << 2;
        const float* zp = z + (size_t)b * CDIM * SEQ + s0 + row;
        #pragma unroll
        for (int kb = kh * 32; kb < kh * 32 + 32; kb += 4) {
            f32x4 v;
            #pragma unroll
            for (int u = 0; u < 4; ++u) v[u] = zp[(size_t)(kb + u) * SEQ];
            *reinterpret_cast<f32x4*>(&zf[(row << 6) | (kb ^ swz)]) = v;
        }
    }
    __syncthreads();

    // ---------- S2: zsq from LDS (t<128; same sequential chain as R6) ------
    if (t < RPB) {
        const int row = t;
        const int swz = (row & 7) << 2;
        float r[8];
        #pragma unroll
        for (int q = 0; q < 8; ++q) r[q] = 0.0f;
        #pragma unroll
        for (int k = 0; k < 64; ++k) {
            const float x = zf[(row << 6) | (k ^ swz)];
            r[k & 7] = __fadd_rn(r[k & 7], __fmul_rn(x, x));   // 0+x^2 exact
        }
        zsq[row] = pair8(r);
    }

    // ---------- S3: z fragments (4 row-tiles x 2 k-steps) in VGPRs ----------
    s16x8 zfr[4][2];
    #pragma unroll
    for (int rt = 0; rt < 4; ++rt) {
        const int row = rw + rt * 16 + ln;
        const int swz = (row & 7) << 2;
        #pragma unroll
        for (int ks = 0; ks < 2; ++ks) {
            const int kb = g * 8 + ks * 32;
            const f32x4 a = *reinterpret_cast<const f32x4*>(&zf[(row << 6) | (kb ^ swz)]);
            const f32x4 c = *reinterpret_cast<const f32x4*>(&zf[(row << 6) | ((kb + 4) ^ swz)]);
            s16x8 fr;
            fr[0] = f2bf(a[0]); fr[1] = f2bf(a[1]); fr[2] = f2bf(a[2]); fr[3] = f2bf(a[3]);
            fr[4] = f2bf(c[0]); fr[5] = f2bf(c[1]); fr[6] = f2bf(c[2]); fr[7] = f2bf(c[3]);
            zfr[rt][ks] = fr;
        }
    }

    // ---------- phase A: scan, per-row approx min ----------
    float mrun[4];
    #pragma unroll
    for (int rt = 0; rt < 4; ++rt) mrun[rt] = INFINITY;

    #pragma unroll 1
    for (int q = 0; q < 8; ++q) {
        s16x8 efr[4][2];
        f32x4 eq[4];
        #pragma unroll
        for (int ct = 0; ct < 4; ++ct) {
            const int code = cw + q * 64 + ct * 16 + ln;
            const unsigned short* ep = ebf + code * 64;
            #pragma unroll
            for (int ks = 0; ks < 2; ++ks)
                efr[ct][ks] = *reinterpret_cast<const s16x8*>(ep + g * 8 + ks * 32);
            eq[ct] = *reinterpret_cast<const f32x4*>(&esq[cw + q * 64 + ct * 16 + g * 4]);
        }
        #pragma unroll
        for (int rt = 0; rt < 4; ++rt) {
            #pragma unroll
            for (int ct = 0; ct < 4; ++ct) {
                f32x4 acc = {0.f, 0.f, 0.f, 0.f};
                acc = __builtin_amdgcn_mfma_f32_16x16x32_bf16(efr[ct][0], zfr[rt][0], acc, 0, 0, 0);
                acc = __builtin_amdgcn_mfma_f32_16x16x32_bf16(efr[ct][1], zfr[rt][1], acc, 0, 0, 0);
                const float d0 = __fmaf_rn(-2.f, acc[0], eq[ct][0]);
                const float d1 = __fmaf_rn(-2.f, acc[1], eq[ct][1]);
                const float d2 = __fmaf_rn(-2.f, acc[2], eq[ct][2]);
                const float d3 = __fmaf_rn(-2.f, acc[3], eq[ct][3]);
                mrun[rt] = fminf(mrun[rt],
                                 fminf(fminf(d0, d1), fminf(d2, d3)));
            }
        }
    }
    #pragma unroll
    for (int rt = 0; rt < 4; ++rt)
        atomicMin(&rowmin[rw + rt * 16 + ln], enc_f32(mrun[rt]));
    __syncthreads();

    // ---------- phase B: rescan, push candidates (thr computed inline) -----
    const float emax = sqrtf(__uint_as_float(emax_u)) * 1.0001f;
    float cthr[4];
    #pragma unroll
    for (int rt = 0; rt < 4; ++rt) {
        const int row = rw + rt * 16 + ln;
        const float thr_row = __fmaf_rn(0.025f * emax, sqrtf(zsq[row]), 1e-4f);
        cthr[rt] = dec_f32(rowmin[row]) + thr_row;
    }
    #pragma unroll 1
    for (int q = 0; q < 8; ++q) {
        s16x8 efr[4][2];
        f32x4 eq[4];
        #pragma unroll
        for (int ct = 0; ct < 4; ++ct) {
            const int code = cw + q * 64 + ct * 16 + ln;
            const unsigned short* ep = ebf + code * 64;
            #pragma unroll
            for (int ks = 0; ks < 2; ++ks)
                efr[ct][ks] = *reinterpret_cast<const s16x8*>(ep + g * 8 + ks * 32);
            eq[ct] = *reinterpret_cast<const f32x4*>(&esq[cw + q * 64 + ct * 16 + g * 4]);
        }
        #pragma unroll
        for (int rt = 0; rt < 4; ++rt) {
            #pragma unroll
            for (int ct = 0; ct < 4; ++ct) {
                f32x4 acc = {0.f, 0.f, 0.f, 0.f};
                acc = __builtin_amdgcn_mfma_f32_16x16x32_bf16(efr[ct][0], zfr[rt][0], acc, 0, 0, 0);
                acc = __builtin_amdgcn_mfma_f32_16x16x32_bf16(efr[ct][1], zfr[rt][1], acc, 0, 0, 0);
                const int row  = rw + rt * 16 + ln;
                const int cbas = cw + q * 64 + ct * 16 + g * 4;
                #pragma unroll
                for (int rr = 0; rr < 4; ++rr) {
                    const float dd = __fmaf_rn(-2.f, acc[rr], eq[ct][rr]);
                    if (dd <= cthr[rt]) {
                        const unsigned idx = atomicAdd(&qcnt, 1u);
                        if (idx < (unsigned)QMAX)
                            queue[idx] = ((unsigned)row << 10) | (unsigned)(cbas + rr);
                    }
                }
            }
        }
    }
    __syncthreads();

    // ---------- phase C: exact rescore (R1 chain, bit-identical) ----------
    const unsigned qtot = qcnt;
    if (qtot <= (unsigned)QMAX) {
        for (unsigned i = t; i < qtot; i += TPB) {
            const unsigned pk = queue[i];
            const int row = (int)(pk >> 10);
            const int j   = (int)(pk & 1023u);
            const int swz = (row & 7) << 2;
            const float* e = emb + j * CDIM;
            float acc = 0.0f;
            #pragma unroll
            for (int k = 0; k < CDIM; ++k)
                acc = __fmaf_rn(zf[(row << 6) | (k ^ swz)], e[k], acc);
            const float d = __fmaf_rn(-2.f, acc, __fadd_rn(zsq[row], esq[j]));
            const unsigned long long key =
                ((unsigned long long)enc_f32(d) << 32) | (unsigned)j;
            atomicMin(&keys[row], key);          // (d asc, then j asc)
        }
    } else {
        // queue overflowed (never expected): provably-correct full rescan
        for (int i = t; i < RPB * N_EMB; i += TPB) {
            const int row = i >> 10;
            const int j   = i & 1023;
            const int swz = (row & 7) << 2;
            const float* e = emb + j * CDIM;
            float acc = 0.0f;
            #pragma unroll
            for (int k = 0; k < CDIM; ++k)
                acc = __fmaf_rn(zf[(row << 6) | (k ^ swz)], e[k], acc);
            const float d = __fmaf_rn(-2.f, acc, __fadd_rn(zsq[row], esq[j]));
            const unsigned long long key =
                ((unsigned long long)enc_f32(d) << 32) | (unsigned)j;
            atomicMin(&keys[row], key);
        }
    }
    __syncthreads();

    // ---------- output: gather emb[jmin] -> (b, c, s) ----------
    {
        const int row = t & 127;
        const int h   = t >> 7;              // c-half
        int jm = (int)(keys[row] & 0xFFFFFFFFull);
        if ((unsigned)jm >= (unsigned)N_EMB) jm = 0;   // safety
        const float* e = emb + (size_t)jm * CDIM + h * 32;
        float* op = out + (size_t)b * CDIM * SEQ + s0 + row;
        #pragma unroll
        for (int c = 0; c < 32; c += 4) {
            const f32x4 v = *reinterpret_cast<const f32x4*>(e + c);
            op[(size_t)(h * 32 + c + 0) * SEQ] = v[0];
            op[(size_t)(h * 32 + c + 1) * SEQ] = v[1];
            op[(size_t)(h * 32 + c + 2) * SEQ] = v[2];
            op[(size_t)(h * 32 + c + 3) * SEQ] = v[3];
        }
    }
}

// ---------------- fallback (R1, known-correct, ~439 us) ----------------
__global__ __launch_bounds__(256, 2) void vq_fallback(
    const float* __restrict__ z, const float* __restrict__ emb,
    float* __restrict__ out)
{
    __shared__ float esq[N_EMB];
    for (int j = threadIdx.x; j < N_EMB; j += 256) {
        const float* e = emb + j * CDIM;
        float r[8];
        #pragma unroll
        for (int q = 0; q < 8; ++q) r[q] = __fmul_rn(e[q], e[q]);
        #pragma unroll
        for (int i = 8; i < 64; i += 8)
            #pragma unroll
            for (int q = 0; q < 8; ++q)
                r[q] = __fadd_rn(r[q], __fmul_rn(e[i + q], e[i + q]));
        esq[j] = pair8(r);
    }
    __syncthreads();
    const int row = blockIdx.x * 256 + threadIdx.x;
    const int b = row >> 12, s = row & (SEQ - 1);
    const float* zp = z + (size_t)b * CDIM * SEQ + s;
    float zv[CDIM];
    #pragma unroll
    for (int k = 0; k < CDIM; ++k) zv[k] = zp[(size_t)k * SEQ];
    float r[8];
    #pragma unroll
    for (int q = 0; q < 8; ++q) r[q] = __fmul_rn(zv[q], zv[q]);
    #pragma unroll
    for (int i = 8; i < 64; i += 8)
        #pragma unroll
        for (int q = 0; q < 8; ++q)
            r[q] = __fadd_rn(r[q], __fmul_rn(zv[i + q], zv[i + q]));
    const float zsq = pair8(r);
    float dmin = INFINITY; int jmin = 0;
    #pragma unroll 1
    for (int j = 0; j < N_EMB; ++j) {
        const float* e = emb + j * CDIM;
        float acc = 0.0f;
        #pragma unroll
        for (int k = 0; k < CDIM; ++k) acc = __fmaf_rn(zv[k], e[k], acc);
        const float d = __fmaf_rn(-2.f, acc, __fadd_rn(zsq, esq[j]));
        if (d < dmin) { dmin = d; jmin = j; }
    }
    const f32x4* ej = reinterpret_cast<const f32x4*>(emb + (size_t)jmin * CDIM);
    float* op = out + (size_t)b * CDIM * SEQ + s;
    #pragma unroll
    for (int q = 0; q < 16; ++q) {
        const f32x4 v = ej[q];
        op[(size_t)(4 * q + 0) * SEQ] = v[0];
        op[(size_t)(4 * q + 1) * SEQ] = v[1];
        op[(size_t)(4 * q + 2) * SEQ] = v[2];
        op[(size_t)(4 * q + 3) * SEQ] = v[3];
    }
}

extern "C" void kernel_launch(void* const* d_in, const int* in_sizes, int n_in,
                              void* d_out, int out_size, void* d_ws, size_t ws_size,
                              hipStream_t stream)
{
    const float* z   = (const float*)d_in[0];
    const float* emb = (const float*)d_in[1];
    float* out = (float*)d_out;

    if (ws_size < WS_EBF_BYTES || d_ws == nullptr) {
        vq_fallback<<<NROWS / 256, 256, 0, stream>>>(z, emb, out);
        return;
    }
    unsigned short* ebf = (unsigned short*)d_ws;

    vq_setup_ebf<<<64, 256, 0, stream>>>(emb, ebf);
    vq_main<<<NROWS / RPB, TPB, 0, stream>>>(z, emb, ebf, out);
}